// Round 3
// baseline (83.041 us; speedup 1.0000x reference)
//
#include <hip/hip_runtime.h>

// Problem constants
#define B_   64
#define L_   1024
#define D_   1280   // 320 float4
#define H1_  640
#define H2_  320
#define NB_  512    // pooling blocks: global row space split into NB_ equal chunks
#define KS_  16     // k-splits for mlp1
#define KC_  80     // 1280/16

// ---------------- Kernel 1: globally-balanced masked partial sums ----------------
// The global valid-row index space [0, total) (total = sum(len_b - 2)) is split
// into NB_ exactly-equal chunks -> perfect load balance regardless of batch_len
// distribution. A chunk fully containing a batch writes pooled[] directly; the
// <=2 boundary partials go to tagged slots consumed by pool_reduce.
__global__ void pool_partial(const float* __restrict__ rep, const int* __restrict__ blen,
                             float* __restrict__ part, int* __restrict__ tags,
                             float* __restrict__ pooled) {
    const int k   = blockIdx.x;     // chunk 0..NB_-1
    const int tid = threadIdx.x;    // 0..319 (float4 lane)

    // total valid rows (uniform scalar scan, L1-cached)
    int total = 0;
    #pragma unroll
    for (int b = 0; b < B_; ++b) total += blen[b] - 2;
    const int G  = (total + NB_ - 1) / NB_;
    const int r0 = k * G;
    const int r1 = min(r0 + G, total);

    float4 accA = make_float4(0.f, 0.f, 0.f, 0.f);
    float4 accB = accA;
    int tagA = -1, tagB = -1;
    bool usedA = false;

    if (r0 < r1) {
        const float4* repv = (const float4*)rep;
        int p = 0;  // prefix of valid rows before batch b
        for (int b = 0; b < B_; ++b) {
            const int n  = blen[b] - 2;
            const int s0 = max(r0, p);
            const int s1 = min(r1, p + n);
            if (s1 > s0) {
                const int l0 = 1 + (s0 - p);   // local row range [l0, l1)
                const int l1 = 1 + (s1 - p);
                float4 acc = make_float4(0.f, 0.f, 0.f, 0.f);
                const float4* base = repv + (size_t)b * L_ * (D_ / 4) + tid;
                #pragma unroll 4
                for (int l = l0; l < l1; ++l) {
                    float4 v = base[(size_t)l * (D_ / 4)];
                    acc.x += v.x; acc.y += v.y; acc.z += v.z; acc.w += v.w;
                }
                const bool full = (s0 == p) && (s1 == p + n);
                if (full) {
                    // sole contributor for this batch: finalize now
                    const float inv = 1.0f / (float)n;
                    float4 o = make_float4(acc.x * inv, acc.y * inv, acc.z * inv, acc.w * inv);
                    ((float4*)pooled)[(size_t)b * (D_ / 4) + tid] = o;
                } else if (!usedA) {
                    accA = acc; tagA = b; usedA = true;
                } else {
                    accB = acc; tagB = b;   // only first/last segment can be partial
                }
            }
            p += n;
            if (p >= r1) break;
        }
    }
    // always write both slots (zeros if unused; tags gate the reduce)
    ((float4*)part)[((size_t)k * 2 + 0) * (D_ / 4) + tid] = accA;
    ((float4*)part)[((size_t)k * 2 + 1) * (D_ / 4) + tid] = accB;
    if (tid == 0) { tags[k * 2] = tagA; tags[k * 2 + 1] = tagB; }
}

// ---------------- Kernel 2: gather tagged boundary partials ----------------
__global__ void pool_reduce(const int* __restrict__ blen, const float* __restrict__ part,
                            const int* __restrict__ tags, float* __restrict__ pooled) {
    const int b   = blockIdx.x;
    const int tid = threadIdx.x;    // 0..319
    int total = 0, pb = 0;
    #pragma unroll
    for (int i = 0; i < B_; ++i) { const int ni = blen[i] - 2; if (i < b) pb += ni; total += ni; }
    const int n  = blen[b] - 2;
    const int G  = (total + NB_ - 1) / NB_;
    const int k0 = pb / G;
    const int k1 = (pb + n - 1) / G;

    float4 acc = make_float4(0.f, 0.f, 0.f, 0.f);
    bool any = false;
    for (int k = k0; k <= k1; ++k) {          // fixed order -> deterministic
        if (tags[2 * k] == b) {
            float4 v = ((const float4*)part)[((size_t)k * 2 + 0) * (D_ / 4) + tid];
            acc.x += v.x; acc.y += v.y; acc.z += v.z; acc.w += v.w; any = true;
        }
        if (tags[2 * k + 1] == b) {
            float4 v = ((const float4*)part)[((size_t)k * 2 + 1) * (D_ / 4) + tid];
            acc.x += v.x; acc.y += v.y; acc.z += v.z; acc.w += v.w; any = true;
        }
    }
    if (any) {  // batches fully inside one chunk were already finalized
        const float inv = 1.0f / (float)n;
        acc.x *= inv; acc.y *= inv; acc.z *= inv; acc.w *= inv;
        ((float4*)pooled)[(size_t)b * (D_ / 4) + tid] = acc;
    }
}

// ---------------- Kernel 3: h-partials = pooled @ W1 (k-split) ----------------
// grid (10 j-tiles of 64, 16 k-splits of 80), block 256.
// Thread owns 16 batches x 1 column. W1 read exactly once grid-wide.
__global__ void mlp1_partial(const float* __restrict__ pooled, const float* __restrict__ W1,
                             float* __restrict__ hpart) {
    const int jt  = blockIdx.x;     // 0..9
    const int ks  = blockIdx.y;     // 0..15
    const int tid = threadIdx.x;    // 0..255
    const int jl  = tid & 63;
    const int b0  = (tid >> 6) * 16;
    const int k0  = ks * KC_;
    const int j0  = jt * 64;

    __shared__ float pl[B_][KC_];   // pooled tile [b][kk]  (20 KB)
    for (int e = tid; e < B_ * KC_; e += 256) {
        int b = e / KC_, kk = e % KC_;
        pl[b][kk] = pooled[(size_t)b * D_ + k0 + kk];
    }
    __syncthreads();

    float acc[16];
    #pragma unroll
    for (int r = 0; r < 16; ++r) acc[r] = 0.f;

    const float* w1p = W1 + (size_t)k0 * H1_ + j0 + jl;
    for (int kk = 0; kk < KC_; kk += 4) {
        const float w0 = w1p[(size_t)(kk + 0) * H1_];
        const float w1 = w1p[(size_t)(kk + 1) * H1_];
        const float w2 = w1p[(size_t)(kk + 2) * H1_];
        const float w3 = w1p[(size_t)(kk + 3) * H1_];
        #pragma unroll
        for (int r = 0; r < 16; ++r) {
            float4 p = *(const float4*)&pl[b0 + r][kk];
            acc[r] = fmaf(p.x, w0, acc[r]);
            acc[r] = fmaf(p.y, w1, acc[r]);
            acc[r] = fmaf(p.z, w2, acc[r]);
            acc[r] = fmaf(p.w, w3, acc[r]);
        }
    }

    float* hp = hpart + (size_t)ks * B_ * H1_;
    #pragma unroll
    for (int r = 0; r < 16; ++r)
        hp[(size_t)(b0 + r) * H1_ + j0 + jl] = acc[r];
}

// ---------------- Kernel 4: h reduce + relu, emb, y ----------------
// block per batch, 320 threads.
__global__ void mlp23(const float* __restrict__ hpart, const float* __restrict__ b1,
                      const float* __restrict__ W2, const float* __restrict__ b2,
                      const float* __restrict__ W3, const float* __restrict__ b3,
                      float* __restrict__ out) {
    const int b   = blockIdx.x;
    const int tid = threadIdx.x;   // 0..319
    __shared__ float hrow[H1_];
    __shared__ float erow[H2_];

    // phase 1: h[b][j] = relu(sum_ks hpart + b1)
    for (int j = tid; j < H1_; j += 320) {
        float s = b1[j];
        #pragma unroll
        for (int ks = 0; ks < KS_; ++ks)
            s += hpart[((size_t)ks * B_ + b) * H1_ + j];
        hrow[j] = fmaxf(s, 0.f);
    }
    __syncthreads();

    // phase 2: emb[b][j] = relu(hrow . W2[:,j] + b2[j]) — 4 accumulators to
    // break the 640-long dependent FMA chain
    {
        const int j = tid;
        float s0 = 0.f, s1 = 0.f, s2 = 0.f, s3 = 0.f;
        #pragma unroll 2
        for (int k = 0; k < H1_; k += 4) {
            s0 = fmaf(hrow[k + 0], W2[(size_t)(k + 0) * H2_ + j], s0);
            s1 = fmaf(hrow[k + 1], W2[(size_t)(k + 1) * H2_ + j], s1);
            s2 = fmaf(hrow[k + 2], W2[(size_t)(k + 2) * H2_ + j], s2);
            s3 = fmaf(hrow[k + 3], W2[(size_t)(k + 3) * H2_ + j], s3);
        }
        float s = fmaxf(b2[j] + ((s0 + s1) + (s2 + s3)), 0.f);
        erow[j] = s;
        out[128 + (size_t)b * H2_ + j] = s;
    }
    __syncthreads();

    // phase 3: y[b][o] = erow . W3[:,o] + b3[o]   (two waves, shuffle reduce)
    if (tid < 128) {
        const int o = tid >> 6, lane = tid & 63;
        float s = 0.f;
        for (int j = lane; j < H2_; j += 64)
            s = fmaf(erow[j], W3[(size_t)j * 2 + o], s);
        #pragma unroll
        for (int off = 32; off >= 1; off >>= 1)
            s += __shfl_down(s, off, 64);
        if (lane == 0) out[(size_t)b * 2 + o] = s + b3[o];
    }
}

extern "C" void kernel_launch(void* const* d_in, const int* in_sizes, int n_in,
                              void* d_out, int out_size, void* d_ws, size_t ws_size,
                              hipStream_t stream) {
    const float* rep  = (const float*)d_in[0];
    const int*   blen = (const int*)  d_in[1];
    const float* W1   = (const float*)d_in[2];
    const float* b1   = (const float*)d_in[3];
    const float* W2   = (const float*)d_in[4];
    const float* b2   = (const float*)d_in[5];
    const float* W3   = (const float*)d_in[6];
    const float* b3   = (const float*)d_in[7];
    float* out = (float*)d_out;

    // workspace layout (floats):
    //   part   NB_*2*D          = 1,310,720  (5.24 MB)
    //   pooled B_*D             =    81,920
    //   hpart  KS_*B_*H1_       =   655,360
    //   tags   NB_*2 ints       =     1,024
    float* ws     = (float*)d_ws;
    float* part   = ws;
    float* pooled = part + (size_t)NB_ * 2 * D_;
    float* hpart  = pooled + (size_t)B_ * D_;
    int*   tags   = (int*)(hpart + (size_t)KS_ * B_ * H1_);

    pool_partial<<<NB_, 320, 0, stream>>>(rep, blen, part, tags, pooled);
    pool_reduce <<<B_, 320, 0, stream>>>(blen, part, tags, pooled);
    mlp1_partial<<<dim3(10, KS_), 256, 0, stream>>>(pooled, W1, hpart);
    mlp23       <<<B_, 320, 0, stream>>>(hpart, b1, W2, b2, W3, b3, out);
}